// Round 23
// baseline (214.446 us; speedup 1.0000x reference)
//
#include <hip/hip_runtime.h>

typedef __attribute__((ext_vector_type(4))) float f32x4;
typedef __attribute__((ext_vector_type(8))) short s16x8;
typedef __attribute__((ext_vector_type(8))) unsigned short u16x8;
typedef __attribute__((ext_vector_type(4))) unsigned short u16x4;

namespace {
constexpr int B_ = 16, C_ = 128, N_ = 8192, K_ = 256, P_ = 128, NB_ = 6;
constexpr int NSP = 16;  // xdown n-splits
}

__device__ __forceinline__ float bf2f(unsigned short h) {
  return __uint_as_float(((unsigned int)h) << 16);
}
__device__ __forceinline__ unsigned short f2bf(float f) {
  unsigned int u = __float_as_uint(f);
  return (unsigned short)((u + 0x7fffu + ((u >> 16) & 1u)) >> 16);
}
// async global->LDS, 16B per lane, lane l writes lds_base + l*16
__device__ __forceinline__ void gload_lds16(const void* gsrc, void* ldsdst) {
  __builtin_amdgcn_global_load_lds(
      (const __attribute__((address_space(1))) void*)gsrc,
      (__attribute__((address_space(3))) void*)ldsdst, 16, 0, 0);
}

// ---------------------------------------------------------------------------
// 0) prep: xh[b][n][c] bf16 + per-(chunk,b,c) IN partials  (xcn eliminated)
// ---------------------------------------------------------------------------
__global__ __launch_bounds__(256) void k_prep(const float* __restrict__ x,
                                              unsigned short* __restrict__ xh,
                                              float* __restrict__ pstS,
                                              float* __restrict__ pstQ) {
  const int chunk = blockIdx.x, b = blockIdx.y;
  const int n0 = chunk * 64;
  __shared__ float ts[64][132];
  __shared__ float rs_[2][128], rq_[2][128];
  const int tid = threadIdx.x;
  for (int i = 0; i < 8; i++) {
    int q = tid + i * 256;
    int n4 = q & 15, c = q >> 4;
    float4 v = *reinterpret_cast<const float4*>(x + (size_t)(b * C_ + c) * N_ + n0 + 4 * n4);
    ts[4 * n4 + 0][c] = v.x; ts[4 * n4 + 1][c] = v.y;
    ts[4 * n4 + 2][c] = v.z; ts[4 * n4 + 3][c] = v.w;
  }
  __syncthreads();
  for (int i = 0; i < 4; i++) {
    int q = tid + i * 256;
    int cg = q & 15, nn = q >> 4;
    u16x8 o;
#pragma unroll
    for (int j = 0; j < 8; j++) o[j] = f2bf(ts[nn][8 * cg + j]);
    *reinterpret_cast<u16x8*>(xh + (size_t)(b * N_ + n0 + nn) * C_ + 8 * cg) = o;
  }
  {
    int c = tid & 127, h = tid >> 7;
    float s = 0.f, ss = 0.f;
    for (int nn = h * 32; nn < h * 32 + 32; nn++) { float v = ts[nn][c]; s += v; ss += v * v; }
    rs_[h][c] = s; rq_[h][c] = ss;
  }
  __syncthreads();
  if (tid < 128) {
    pstS[(chunk * 16 + b) * 128 + tid] = rs_[0][tid] + rs_[1][tid];
    pstQ[(chunk * 16 + b) * 128 + tid] = rq_[0][tid] + rq_[1][tid];
  }
}

// 0b) convert all weights to bf16 once
__global__ __launch_bounds__(256) void k_wconv(const float* __restrict__ dpw,
                                               const float* __restrict__ duw,
                                               const float* __restrict__ scw,
                                               const float* __restrict__ w1,
                                               const float* __restrict__ w2,
                                               unsigned short* __restrict__ dpwh,
                                               unsigned short* __restrict__ duwh,
                                               unsigned short* __restrict__ scah,
                                               unsigned short* __restrict__ scbh,
                                               unsigned short* __restrict__ w1sh,
                                               unsigned short* __restrict__ w1bh,
                                               unsigned short* __restrict__ w2h) {
  int t = blockIdx.x * 256 + threadIdx.x;
  if (t < 65536) {
    int o = t >> 8, k = t & 255;
    float vb = w1[(size_t)o * 512 + 256 + k];
    w1sh[t] = f2bf(w1[(size_t)o * 512 + k] + vb);
    w1bh[t] = f2bf(vb);
    w2h[t] = f2bf(w2[t]);
  }
  if (t < 32768) { dpwh[t] = f2bf(dpw[t]); duwh[t] = f2bf(duw[t]); }
  if (t < 16384) {
    int o = t >> 7, c = t & 127;
    scah[t] = f2bf(scw[o * 256 + c]);
    scbh[t] = f2bf(scw[o * 256 + 128 + c]);
  }
}

// 0c) finalize instance-norm stats per (b,c): 8 blocks x 256 threads
__global__ __launch_bounds__(256) void k_instat_fin(const float* __restrict__ pstS,
                                                    const float* __restrict__ pstQ,
                                                    float* __restrict__ m_o,
                                                    float* __restrict__ v_o,
                                                    float* __restrict__ r_o) {
  int e = blockIdx.x * 256 + threadIdx.x;  // b*128+c (2048)
  int b = e >> 7, c = e & 127;
  float s = 0.f, q = 0.f;
  for (int ch = 0; ch < 128; ch++) {
    s += pstS[(ch * 16 + b) * 128 + c];
    q += pstQ[(ch * 16 + b) * 128 + c];
  }
  float m = s / N_;
  float v = q / N_ - m * m;
  m_o[e] = m; v_o[e] = v; r_o[e] = rsqrtf(v + 1e-3f);
}

// 2) fold IN+BN into per-(b,c) affine (BN mean of IN(x) is analytically 0)
__global__ void k_affine(const float* __restrict__ m_in, const float* __restrict__ v_in,
                         const float* __restrict__ r_in,
                         const float* __restrict__ dpg, const float* __restrict__ dpb,
                         const float* __restrict__ dug, const float* __restrict__ dub,
                         float* __restrict__ a_dp, float* __restrict__ d_dp,
                         float* __restrict__ a_du, float* __restrict__ d_du) {
  int c = threadIdx.x;  // 128 threads
  float V = 0.f;
  for (int b = 0; b < B_; b++) { float v = v_in[b * C_ + c]; V += v / (v + 1e-3f); }
  V *= (1.f / B_);
  float R = rsqrtf(V + 1e-5f);
  float gdp = dpg[c], bdp = dpb[c], gdu = dug[c], bdu = dub[c];
  for (int b = 0; b < B_; b++) {
    int i = b * C_ + c;
    float r = r_in[i], m = m_in[i];
    float sdp = r * R * gdp;
    a_dp[i] = sdp; d_dp[i] = -m * sdp + bdp;
    float sdu = r * R * gdu;
    a_du[i] = sdu; d_du[i] = -m * sdu + bdu;
  }
}

// ---------------------------------------------------------------------------
// 3+5 fused (dp path), v8: xcn eliminated. Raw X chunk staged -> bufR; one
//   "produce" pass emits bufH (transform, vector) + bufC (raw transpose,
//   scalar). 3 barriers/chunk, same pipeline as v7. LDS ~147 KB, 1 block/CU.
// ---------------------------------------------------------------------------
__global__ __launch_bounds__(512) void k_dp_fused(const unsigned short* __restrict__ xh,
                                                  const unsigned short* __restrict__ dpwh,
                                                  const float* __restrict__ a_dp,
                                                  const float* __restrict__ d_dp,
                                                  const float* __restrict__ dpbias,
                                                  float* __restrict__ part,
                                                  float* __restrict__ pS) {
  const int sp = blockIdx.x, b = blockIdx.y;
  const int nbase = sp * (N_ / NSP);  // 512-point split
  __shared__ __align__(16) unsigned short bufW[256 * 128];  // 64 KB [k][c]
  __shared__ __align__(16) unsigned short bufR[64 * 128];   // 16 KB raw x [n][c]
  __shared__ __align__(16) unsigned short bufH[64 * 128];   // 16 KB h [n][c]
  __shared__ __align__(16) unsigned short bufP[256 * 64];   // 32 KB P [k][n]
  __shared__ __align__(16) unsigned short bufC[128 * 64];   // 16 KB x^T [c][n]
  __shared__ float bias_s[256], aff_as[128], aff_ds[128];
  const int tid = threadIdx.x, lane = tid & 63, wid = tid >> 6;  // 8 waves
  const int wr = wid >> 1, wc = wid & 1, l15 = lane & 15, l4 = lane >> 4;
  if (tid < 256) bias_s[tid] = dpbias[tid];
  if (tid < 128) { aff_as[tid] = a_dp[b * C_ + tid]; aff_ds[tid] = d_dp[b * C_ + tid]; }
  // stage full W [256 k][128 c]: 64 calls, 8 per wave
#pragma unroll
  for (int i = 0; i < 8; i++) {
    int call = wid * 8 + i;
    int row = call * 4 + (lane >> 4);
    int gch = (lane & 15) ^ (row & 7);
    gload_lds16(dpwh + (size_t)row * C_ + gch * 8, bufW + call * 512);
  }
  // prologue: stage X(0) raw -> bufR
#pragma unroll
  for (int i = 0; i < 2; i++) {
    int call = wid * 2 + i;
    int row = call * 4 + (lane >> 4);
    int gch = (lane & 15) ^ (row & 7);
    gload_lds16(xh + (size_t)(b * N_ + nbase + row) * C_ + gch * 8, bufR + call * 512);
  }
  __syncthreads();  // W + X(0) staged
  // produce(0): bufH = relu(a*bufR+d); bufC = transpose(bufR)
#pragma unroll
  for (int i = 0; i < 2; i++) {
    int q = tid + i * 512;
    int row = q >> 4, p = q & 15;
    int cb = (p ^ (row & 7)) * 8;
    u16x8 v = *reinterpret_cast<const u16x8*>(bufR + q * 8);
    u16x8 h;
#pragma unroll
    for (int j = 0; j < 8; j++) {
      h[j] = f2bf(fmaxf(fmaf(aff_as[cb + j], bf2f(v[j]), aff_ds[cb + j]), 0.f));
      int c = cb + j;
      bufC[c * 64 + ((((row >> 3) ^ (c & 7)) << 3) | (row & 7))] = v[j];
    }
    *reinterpret_cast<u16x8*>(bufH + q * 8) = h;
  }
  __syncthreads();  // bufH + bufC visible
  s16x8 onesf;
#pragma unroll
  for (int j = 0; j < 8; j++) onesf[j] = (short)0x3F80;  // bf16 1.0
  f32x4 acc2[2][8] = {};
  f32x4 accS[8] = {};
  for (int nc = 0; nc < N_ / NSP; nc += 64) {
    const int n0n = nbase + nc + 64;  // next chunk base
    const bool more = (nc + 64) < (N_ / NSP);
    // MFMA1 embed: acc1[k 256][n 64] — raw fragments both sides
    f32x4 acc1[4][2] = {};
#pragma unroll
    for (int ks = 0; ks < 128; ks += 32) {
      const int ch = (ks >> 3) + l4;
      s16x8 af[4], bh[2];
#pragma unroll
      for (int m = 0; m < 4; m++) {
        int row = wr * 64 + m * 16 + l15;
        af[m] = *reinterpret_cast<const s16x8*>(bufW + row * 128 + ((ch ^ (row & 7)) << 3));
      }
#pragma unroll
      for (int nq = 0; nq < 2; nq++) {
        int row = wc * 32 + nq * 16 + l15;
        bh[nq] = *reinterpret_cast<const s16x8*>(bufH + row * 128 + ((ch ^ (row & 7)) << 3));
      }
#pragma unroll
      for (int m = 0; m < 4; m++)
#pragma unroll
        for (int nq = 0; nq < 2; nq++)
          acc1[m][nq] = __builtin_amdgcn_mfma_f32_16x16x32_bf16(af[m], bh[nq], acc1[m][nq], 0, 0, 0);
    }
    // P = exp(acc1 + bias) -> bufP (separate buffer)
#pragma unroll
    for (int m = 0; m < 4; m++)
#pragma unroll
      for (int nq = 0; nq < 2; nq++) {
        int kl = wr * 64 + m * 16 + 4 * l4;
        int nl = wc * 32 + nq * 16 + l15;
#pragma unroll
        for (int r = 0; r < 4; r++) {
          unsigned short v = f2bf(__expf(acc1[m][nq][r] + bias_s[kl + r]));
          bufP[(kl + r) * 64 + ((((nl >> 3) ^ ((kl + r) & 7)) << 3) | (nl & 7))] = v;
        }
      }
    __syncthreads();  // B1: P visible; MFMA1 done; bufR free
    // issue X(next) raw -> bufR — lands under MFMA2, drained at B2
    if (more) {
#pragma unroll
      for (int i = 0; i < 2; i++) {
        int call = wid * 2 + i;
        int row = call * 4 + (lane >> 4);
        int gch = (lane & 15) ^ (row & 7);
        gload_lds16(xh + (size_t)(b * N_ + n0n + row) * C_ + gch * 8, bufR + call * 512);
      }
    }
    // MFMA2 xdown: acc2[c 128][k 256] += x @ P^T; ones-row -> accS (wr==0 only)
#pragma unroll
    for (int ks = 0; ks < 64; ks += 32) {
      const int ch = (ks >> 3) + l4;
      s16x8 af2[2], bp[8];
#pragma unroll
      for (int m = 0; m < 2; m++) {
        int row = wr * 32 + m * 16 + l15;
        af2[m] = *reinterpret_cast<const s16x8*>(bufC + row * 64 + ((ch ^ (row & 7)) << 3));
      }
#pragma unroll
      for (int nn = 0; nn < 8; nn++) {
        int row = wc * 128 + nn * 16 + l15;
        bp[nn] = *reinterpret_cast<const s16x8*>(bufP + row * 64 + ((ch ^ (row & 7)) << 3));
      }
#pragma unroll
      for (int m = 0; m < 2; m++)
#pragma unroll
        for (int nn = 0; nn < 8; nn++)
          acc2[m][nn] = __builtin_amdgcn_mfma_f32_16x16x32_bf16(af2[m], bp[nn], acc2[m][nn], 0, 0, 0);
      if (wr == 0) {
#pragma unroll
        for (int nn = 0; nn < 8; nn++)
          accS[nn] = __builtin_amdgcn_mfma_f32_16x16x32_bf16(onesf, bp[nn], accS[nn], 0, 0, 0);
      }
    }
    __syncthreads();  // B2: MFMA2 done (bufC/bufP free); X(next) drained
    if (more) {
      // produce(next): bufH = transform(bufR), bufC = transpose(bufR)
#pragma unroll
      for (int i = 0; i < 2; i++) {
        int q = tid + i * 512;
        int row = q >> 4, p = q & 15;
        int cb = (p ^ (row & 7)) * 8;
        u16x8 v = *reinterpret_cast<const u16x8*>(bufR + q * 8);
        u16x8 h;
#pragma unroll
        for (int j = 0; j < 8; j++) {
          h[j] = f2bf(fmaxf(fmaf(aff_as[cb + j], bf2f(v[j]), aff_ds[cb + j]), 0.f));
          int c = cb + j;
          bufC[c * 64 + ((((row >> 3) ^ (c & 7)) << 3) | (row & 7))] = v[j];
        }
        *reinterpret_cast<u16x8*>(bufH + q * 8) = h;
      }
      __syncthreads();  // B3: bufH + bufC visible
    }
  }
#pragma unroll
  for (int m = 0; m < 2; m++)
#pragma unroll
    for (int nn = 0; nn < 8; nn++) {
      int c = wr * 32 + m * 16 + 4 * l4;
      int k = wc * 128 + nn * 16 + l15;
#pragma unroll
      for (int r = 0; r < 4; r++)
        part[((size_t)(sp * B_ + b) * C_ + c + r) * K_ + k] = acc2[m][nn][r];
    }
  if (wr == 0 && l4 == 0) {
#pragma unroll
    for (int nn = 0; nn < 8; nn++)
      pS[((size_t)sp * 16 + b) * 256 + wc * 128 + nn * 16 + l15] = accS[nn][0];
  }
}

// 4a) rden[b][k] = 1 / sum over NSP split partials
__global__ __launch_bounds__(256) void k_rowfin(const float* __restrict__ pS,
                                                float* __restrict__ rden) {
  int e = blockIdx.x * 256 + threadIdx.x;  // b*256+k (4096)
  int b = e >> 8, k = e & 255;
  float s = 0.f;
  for (int sp = 0; sp < NSP; sp++) s += pS[((size_t)sp * 16 + b) * 256 + k];
  rden[e] = 1.f / s;
}

// 6) reduce split partials, scale by 1/den -> xd fp32 [b][p][k] + xdh bf16
__global__ __launch_bounds__(256) void k_xdown_red(const float* __restrict__ part,
                                                   const float* __restrict__ rden,
                                                   float* __restrict__ xd,
                                                   unsigned short* __restrict__ xdh) {
  int e = blockIdx.x * 256 + threadIdx.x;  // B*C*K
  int k = e % K_;
  int b = e / (K_ * C_);
  float s = 0.f;
  for (int sp = 0; sp < NSP; sp++) s += part[(size_t)sp * (B_ * C_ * K_) + e];
  float v = s * rden[b * K_ + k];
  xd[e] = v;
  xdh[e] = f2bf(v);
}

// ---------------------------------------------------------------------------
// 7) fused gram + sq + top-6: grid (16, 16), 8 p-rows per block.
// ---------------------------------------------------------------------------
__global__ __launch_bounds__(256) void k_knn(const float* __restrict__ xd,
                                             int* __restrict__ idx) {
  const int p0 = blockIdx.x * 8, b = blockIdx.y;
  __shared__ float A[8][256];
  __shared__ float Bt[32][132];
  __shared__ float pd_s[8][129];
  __shared__ float sq_s[128], sqh[128];
  const int tid = threadIdx.x;
#pragma unroll
  for (int i = 0; i < 2; i++) {
    int t = tid + i * 256;
    int pp = t >> 6, k4 = t & 63;
    float4 v = *reinterpret_cast<const float4*>(xd + (size_t)(b * C_ + p0 + pp) * K_ + 4 * k4);
    *reinterpret_cast<float4*>(&A[pp][4 * k4]) = v;
  }
  const int q = tid & 127, h = tid >> 7;
  float acc[4] = {};
  float sqacc = 0.f;
  for (int k0 = 0; k0 < K_; k0 += 32) {
    for (int i = 0; i < 4; i++) {
      int t = tid + i * 256;
      int qq = t >> 3, k4 = t & 7;
      float4 v = *reinterpret_cast<const float4*>(xd + (size_t)(b * C_ + qq) * K_ + k0 + 4 * k4);
      Bt[4 * k4 + 0][qq] = v.x; Bt[4 * k4 + 1][qq] = v.y;
      Bt[4 * k4 + 2][qq] = v.z; Bt[4 * k4 + 3][qq] = v.w;
    }
    __syncthreads();
    for (int kk = 0; kk < 32; ++kk) {
      float bv = Bt[kk][q];
#pragma unroll
      for (int i = 0; i < 4; ++i) acc[i] = fmaf(A[h * 4 + i][k0 + kk], bv, acc[i]);
    }
    {
      float s = 0.f;
      for (int kk = h * 16; kk < h * 16 + 16; kk++) { float v = Bt[kk][q]; s += v * v; }
      sqacc += s;
    }
    __syncthreads();
  }
  if (h == 1) sqh[q] = sqacc;
#pragma unroll
  for (int i = 0; i < 4; ++i) pd_s[h * 4 + i][q] = acc[i];
  __syncthreads();
  if (tid < 128) sq_s[tid] = sqacc + sqh[tid];
  __syncthreads();
  const int wv = tid >> 6, lane = tid & 63;
  for (int r = 0; r < 2; r++) {
    int p = wv * 2 + r;
    float v0 = 2.f * pd_s[p][lane] - sq_s[lane];
    float v1 = 2.f * pd_s[p][lane + 64] - sq_s[lane + 64];
    int q0 = lane, q1 = lane + 64;
#pragma unroll
    for (int j = 0; j < NB_; j++) {
      float bv; int bq;
      if (v0 > v1 || (v0 == v1 && q0 < q1)) { bv = v0; bq = q0; } else { bv = v1; bq = q1; }
#pragma unroll
      for (int o = 32; o > 0; o >>= 1) {
        float ov = __shfl_xor(bv, o); int oq = __shfl_xor(bq, o);
        if (ov > bv || (ov == bv && oq < bq)) { bv = ov; bq = oq; }
      }
      if (lane == 0) idx[(b * P_ + p0 + p) * NB_ + j] = bq;
      if (q0 == bq) v0 = -3.0e38f;
      if (q1 == bq) v1 = -3.0e38f;
    }
  }
}

// ---------------------------------------------------------------------------
// 8) UV via MFMA: Ut/Vt[b][p][o] = sum_k W1{sum|b}[o][k] * xdh[b][p][k]
// ---------------------------------------------------------------------------
__global__ __launch_bounds__(256) void k_uv_mfma(const unsigned short* __restrict__ xdh,
                                                 const unsigned short* __restrict__ w1sh,
                                                 const unsigned short* __restrict__ w1bh,
                                                 float* __restrict__ Ut, float* __restrict__ Vt) {
  const int o0 = blockIdx.x * 128, which = blockIdx.y, b = blockIdx.z;
  __shared__ __align__(16) unsigned char smemraw[128 * 132 * 4];
  unsigned short* tA = (unsigned short*)smemraw;
  unsigned short* tB = tA + 128 * 128;
  const unsigned short* wsel = which ? w1bh : w1sh;
  const int tid = threadIdx.x, lane = tid & 63, wid = tid >> 6;
  const int wr = wid >> 1, wc = wid & 1, l15 = lane & 15, l4 = lane >> 4;
  f32x4 acc[4][4] = {};
  for (int kh = 0; kh < 256; kh += 128) {
#pragma unroll
    for (int i = 0; i < 8; i++) {
      int call = wid * 8 + i;
      int row = call * 4 + (lane >> 4);
      int gch = (lane & 15) ^ (row & 7);
      gload_lds16(wsel + (size_t)(o0 + row) * 256 + kh + gch * 8, tA + call * 512);
      gload_lds16(xdh + (size_t)(b * P_ + row) * 256 + kh + gch * 8, tB + call * 512);
    }
    __syncthreads();
#pragma unroll
    for (int ks = 0; ks < 128; ks += 32) {
      const int ch = (ks >> 3) + l4;
      s16x8 af[4], bfv[4];
#pragma unroll
      for (int m = 0; m < 4; m++) {
        int row = wr * 64 + m * 16 + l15;
        af[m] = *reinterpret_cast<const s16x8*>(tA + row * 128 + ((ch ^ (row & 7)) << 3));
      }
#pragma unroll
      for (int n = 0; n < 4; n++) {
        int row = wc * 64 + n * 16 + l15;
        bfv[n] = *reinterpret_cast<const s16x8*>(tB + row * 128 + ((ch ^ (row & 7)) << 3));
      }
#pragma unroll
      for (int m = 0; m < 4; m++)
#pragma unroll
        for (int n = 0; n < 4; n++)
          acc[m][n] = __builtin_amdgcn_mfma_f32_16x16x32_bf16(af[m], bfv[n], acc[m][n], 0, 0, 0);
    }
    __syncthreads();
  }
  float (*ef)[132] = (float(*)[132])smemraw;
#pragma unroll
  for (int m = 0; m < 4; m++)
#pragma unroll
    for (int n = 0; n < 4; n++) {
      int ol = wr * 64 + m * 16 + 4 * l4;
      int pl = wc * 64 + n * 16 + l15;
#pragma unroll
      for (int r = 0; r < 4; r++) ef[pl][ol + r] = acc[m][n][r];
    }
  __syncthreads();
  float* outp = which ? Vt : Ut;
  for (int i = 0; i < 16; i++) {
    int q = tid + i * 256;
    int pl = q >> 5, c4 = q & 31;
    float4 v = *reinterpret_cast<const float4*>(&ef[pl][c4 * 4]);
    *reinterpret_cast<float4*>(outp + (size_t)(b * P_ + pl) * 256 + o0 + c4 * 4) = v;
  }
}

// 9) g1h[b*768+pj][o] = Ut[b][p][o] + b1[o] - Vt[b][q][o]   (bf16, coalesced)
__global__ __launch_bounds__(256) void k_edge_t(const float* __restrict__ Ut,
                                                const float* __restrict__ Vt,
                                                const int* __restrict__ idx,
                                                const float* __restrict__ b1,
                                                unsigned short* __restrict__ g1h) {
  __shared__ float b1s[256];
  const int tid = threadIdx.x;
  b1s[tid] = b1[tid];
  __syncthreads();
  const int row0 = blockIdx.x * 16;
  for (int r = 0; r < 16; r++) {
    int row = row0 + r;  // b*768 + p*6 + j
    int b = row / 768, pj = row % 768, p = pj / 6;
    int q = idx[(b * P_ + p) * NB_ + (pj % 6)];
    float v = Ut[(size_t)(b * P_ + p) * 256 + tid] + b1s[tid]
            - Vt[(size_t)(b * P_ + q) * 256 + tid];
    g1h[(size_t)row * 256 + tid] = f2bf(v);
  }
}

// 10) BN stats over rows of gt [12288][256]: per-block partial sums
__global__ __launch_bounds__(256) void k_bnstat_t(const unsigned short* __restrict__ gt,
                                                  float* __restrict__ partS,
                                                  float* __restrict__ partQ) {
  const int tid = threadIdx.x;
  const size_t row0 = (size_t)blockIdx.x * 256;
  float s = 0.f, ss = 0.f;
  for (int r = 0; r < 256; r++) {
    float v = bf2f(gt[(row0 + r) * 256 + tid]);
    s += v; ss += v * v;
  }
  partS[blockIdx.x * 256 + tid] = s;
  partQ[blockIdx.x * 256 + tid] = ss;
}

// 11) conv2 via MFMA (bn1 finalize folded in)
__global__ __launch_bounds__(256) void k_conv2_mfma(const unsigned short* __restrict__ g1h,
                                                    const unsigned short* __restrict__ w2h,
                                                    const float* __restrict__ b2,
                                                    const float* __restrict__ partS,
                                                    const float* __restrict__ partQ,
                                                    const float* __restrict__ gamma,
                                                    const float* __restrict__ beta,
                                                    unsigned short* __restrict__ g2h) {
  const int n0 = blockIdx.x * 128, o0 = blockIdx.y * 128, b = blockIdx.z;
  __shared__ __align__(16) unsigned short smem[2 * 128 * 128];
  unsigned short* tA = smem;
  unsigned short* tB = smem + 128 * 128;
  __shared__ float scs[256], shs[256], b2s[128];
  const int tid = threadIdx.x, lane = tid & 63, wid = tid >> 6;
  const int wr = wid >> 1, wc = wid & 1, l15 = lane & 15, l4 = lane >> 4;
  {
    float s = 0.f, q = 0.f;
    for (int i = 0; i < 48; i++) { s += partS[i * 256 + tid]; q += partQ[i * 256 + tid]; }
    const float cnt = (float)(B_ * P_ * NB_);
    float m = s / cnt, var = q / cnt - m * m;
    float scale = gamma[tid] * rsqrtf(var + 1e-5f);
    scs[tid] = scale; shs[tid] = -m * scale + beta[tid];
  }
  if (tid < 128) b2s[tid] = b2[o0 + tid];
  f32x4 acc[4][4] = {};
  for (int kh = 0; kh < 256; kh += 128) {
#pragma unroll
    for (int i = 0; i < 8; i++) {
      int call = wid * 8 + i;
      int row = call * 4 + (lane >> 4);
      int gch = (lane & 15) ^ (row & 7);
      gload_lds16(w2h + (size_t)(o0 + row) * 256 + kh + gch * 8, tA + call * 512);
      gload_lds16(g1h + (size_t)(b * 768 + n0 + row) * 256 + kh + gch * 8, tB + call * 512);
    }
    __syncthreads();
#pragma unroll
    for (int ks = 0; ks < 128; ks += 32) {
      const int ch = (ks >> 3) + l4;
      s16x8 af[4], bfv[4];
#pragma unroll
      for (int m = 0; m < 4; m++) {
        int row = wr * 64 + m * 16 + l15;
        af[m] = *reinterpret_cast<const s16x8*>(tA + row * 128 + ((ch ^ (row & 7)) << 3));
      }
#pragma unroll
      for (int n = 0; n < 4; n++) {
        int row = wc * 64 + n * 16 + l15;
        s16x8 raw = *reinterpret_cast<const s16x8*>(tB + row * 128 + ((ch ^ (row & 7)) << 3));
        s16x8 h;
#pragma unroll
        for (int j = 0; j < 8; j++) {
          int c = kh + ks + 8 * l4 + j;
          h[j] = (short)f2bf(fmaxf(fmaf(scs[c], bf2f((unsigned short)raw[j]), shs[c]), 0.f));
        }
        bfv[n] = h;
      }
#pragma unroll
      for (int m = 0; m < 4; m++)
#pragma unroll
        for (int n = 0; n < 4; n++)
          acc[m][n] = __builtin_amdgcn_mfma_f32_16x16x32_bf16(af[m], bfv[n], acc[m][n], 0, 0, 0);
    }
    __syncthreads();
  }
  unsigned short (*e_s)[136] = reinterpret_cast<unsigned short(*)[136]>(smem);
#pragma unroll
  for (int m = 0; m < 4; m++)
#pragma unroll
    for (int n = 0; n < 4; n++) {
      int ol = wr * 64 + m * 16 + 4 * l4;
      int nl = wc * 64 + n * 16 + l15;
#pragma unroll
      for (int r = 0; r < 4; r++)
        e_s[nl][ol + r] = f2bf(acc[m][n][r] + b2s[ol + r]);
    }
  __syncthreads();
  for (int i = 0; i < 8; i++) {
    int q = tid + i * 256;
    int og = q & 15, nl = q >> 4;
    u16x8 v = *reinterpret_cast<const u16x8*>(&e_s[nl][8 * og]);
    *reinterpret_cast<u16x8*>(g2h + (size_t)(b * 768 + n0 + nl) * 256 + o0 + 8 * og) = v;
  }
}

// 13) gmaxh[b][k][p] = max_j relu(bn2(g2h[b*768+p*6+j][k]))  (bn2 folded in)
__global__ __launch_bounds__(256) void k_gmax_t(const unsigned short* __restrict__ g2h,
                                                const float* __restrict__ partS,
                                                const float* __restrict__ partQ,
                                                const float* __restrict__ gamma,
                                                const float* __restrict__ beta,
                                                unsigned short* __restrict__ gmaxh) {
  const int o0 = blockIdx.x * 128, b = blockIdx.y;
  __shared__ float scS[128], shS[128];
  const int tid = threadIdx.x;
  if (tid < 128) {
    int o = o0 + tid;
    float s = 0.f, q = 0.f;
    for (int i = 0; i < 48; i++) { s += partS[i * 256 + o]; q += partQ[i * 256 + o]; }
    const float cnt = (float)(B_ * P_ * NB_);
    float m = s / cnt, var = q / cnt - m * m;
    float scale = gamma[o] * rsqrtf(var + 1e-5f);
    scS[tid] = scale; shS[tid] = -m * scale + beta[o];
  }
  __syncthreads();
  const int ol = tid & 127, ph = tid >> 7;
  const int o = o0 + ol;
  const float sc = scS[ol], sh = shS[ol];
  for (int p8 = ph * 64; p8 < ph * 64 + 64; p8 += 8) {
    u16x8 pack;
#pragma unroll
    for (int pi = 0; pi < 8; pi++) {
      int p = p8 + pi;
      float m = 0.f;
#pragma unroll
      for (int j = 0; j < NB_; j++) {
        float v = bf2f(g2h[(size_t)(b * 768 + p * 6 + j) * 256 + o]);
        m = fmaxf(m, fmaf(sc, v, sh));
      }
      pack[pi] = f2bf(m);
    }
    *reinterpret_cast<u16x8*>(gmaxh + (size_t)(b * 256 + o) * P_ + p8) = pack;
  }
}

// 14) M2h[b][o2][k] = sum_c scwB[o2][c] * gmaxh[b][k][c]  (MFMA)
__global__ __launch_bounds__(256) void k_m2_mfma(const unsigned short* __restrict__ gmaxh,
                                                 const unsigned short* __restrict__ scbh,
                                                 unsigned short* __restrict__ M2h) {
  const int k0 = blockIdx.x * 128, b = blockIdx.y;
  __shared__ __align__(16) unsigned short smem[2 * 128 * 128];
  unsigned short* tA = smem;
  unsigned short* tB = smem + 128 * 128;
  const int tid = threadIdx.x, lane = tid & 63, wid = tid >> 6;
  const int wr = wid >> 1, wc = wid & 1, l15 = lane & 15, l4 = lane >> 4;
#pragma unroll
  for (int i = 0; i < 8; i++) {
    int call = wid * 8 + i;
    int row = call * 4 + (lane >> 4);
    int gch = (lane & 15) ^ (row & 7);
    gload_lds16(scbh + (size_t)row * P_ + gch * 8, tA + call * 512);
    gload_lds16(gmaxh + (size_t)(b * 256 + k0 + row) * P_ + gch * 8, tB + call * 512);
  }
  __syncthreads();
  f32x4 acc[4][4] = {};
#pragma unroll
  for (int ks = 0; ks < 128; ks += 32) {
    const int ch = (ks >> 3) + l4;
    s16x8 af[4], bfv[4];
#pragma unroll
    for (int m = 0; m < 4; m++) {
      int row = wr * 64 + m * 16 + l15;
      af[m] = *reinterpret_cast<const s16x8*>(tA + row * 128 + ((ch ^ (row & 7)) << 3));
    }
#pragma unroll
    for (int n = 0; n < 4; n++) {
      int row = wc * 64 + n * 16 + l15;
      bfv[n] = *reinterpret_cast<const s16x8*>(tB + row * 128 + ((ch ^ (row & 7)) << 3));
    }
#pragma unroll
    for (int m = 0; m < 4; m++)
#pragma unroll
      for (int n = 0; n < 4; n++)
        acc[m][n] = __builtin_amdgcn_mfma_f32_16x16x32_bf16(af[m], bfv[n], acc[m][n], 0, 0, 0);
  }
  __syncthreads();
  unsigned short (*e_s)[136] = reinterpret_cast<unsigned short(*)[136]>(smem);
#pragma unroll
  for (int m = 0; m < 4; m++)
#pragma unroll
    for (int n = 0; n < 4; n++) {
      int ol = wr * 64 + m * 16 + 4 * l4;
      int kl = wc * 64 + n * 16 + l15;
#pragma unroll
      for (int r = 0; r < 4; r++)
        e_s[ol + r][kl] = f2bf(acc[m][n][r]);
    }
  __syncthreads();
  for (int i = 0; i < 8; i++) {
    int q = tid + i * 256;
    int kg = q & 15, oo = q >> 4;
    u16x8 v = *reinterpret_cast<const u16x8*>(&e_s[oo][8 * kg]);
    *reinterpret_cast<u16x8*>(M2h + (size_t)(b * C_ + oo) * K_ + k0 + 8 * kg) = v;
  }
}

// ---------------------------------------------------------------------------
// 15+16 fused (du path), v8: v7 + M2 stage issued BEFORE the exp epilogue
//   (HBM latency hides under the exp VALU). 512 threads, 8 waves.
// ---------------------------------------------------------------------------
__global__ __launch_bounds__(512) void k_final_f(const unsigned short* __restrict__ xh,
                                                 const unsigned short* __restrict__ duwh,
                                                 const float* __restrict__ dubias,
                                                 const float* __restrict__ a_du,
                                                 const float* __restrict__ d_du,
                                                 const unsigned short* __restrict__ M2h,
                                                 const unsigned short* __restrict__ scah,
                                                 const float* __restrict__ scb,
                                                 float* __restrict__ out) {
  const int n0 = blockIdx.x * 64, b = blockIdx.y;
  __shared__ __align__(16) unsigned short bufX[64 * 128];   // 16 KB xh->h [n][c]
  __shared__ __align__(16) unsigned short bufA[128 * 128];  // 32 KB scah / W half / M2 half
  __shared__ __align__(16) unsigned short bufP[64 * 128];   // 16 KB P half [n][k]
  __shared__ float aff_as[128], aff_ds[128], scb_s[128], bias_s[128];
  __shared__ float psum_s[64], psum2[4][64];
  const int tid = threadIdx.x, lane = tid & 63, wid = tid >> 6;  // 8 waves
  const int wr = wid >> 1, wc = wid & 1, l15 = lane & 15, l4 = lane >> 4;  // wr 0..3
  if (tid < 128) {
    aff_as[tid] = a_du[b * C_ + tid];
    aff_ds[tid] = d_du[b * C_ + tid];
    scb_s[tid] = scb[tid];
  }
  if (tid < 64) psum_s[tid] = 0.f;
  // stage raw xh tile (16 calls, 2/wave) + scah (32 calls, 4/wave)
#pragma unroll
  for (int i = 0; i < 2; i++) {
    int call = wid * 2 + i;
    int row = call * 4 + (lane >> 4);
    int gch = (lane & 15) ^ (row & 7);
    gload_lds16(xh + (size_t)(b * N_ + n0 + row) * C_ + gch * 8, bufX + call * 512);
  }
#pragma unroll
  for (int i = 0; i < 4; i++) {
    int call = wid * 4 + i;
    int row = call * 4 + (lane >> 4);
    int gch = (lane & 15) ^ (row & 7);
    gload_lds16(scah + (size_t)row * C_ + gch * 8, bufA + call * 512);
  }
  __syncthreads();
  // phase A: accA = scah[o][c] @ raw xh[n][c]; o split over 4 wr, n over 2 wc
  f32x4 accA[2][2] = {};
#pragma unroll
  for (int ks = 0; ks < 128; ks += 32) {
    const int ch = (ks >> 3) + l4;
    s16x8 af[2], bh[2];
#pragma unroll
    for (int m = 0; m < 2; m++) {
      int row = wr * 32 + m * 16 + l15;
      af[m] = *reinterpret_cast<const s16x8*>(bufA + row * 128 + ((ch ^ (row & 7)) << 3));
    }
#pragma unroll
    for (int nq = 0; nq < 2; nq++) {
      int row = wc * 32 + nq * 16 + l15;
      bh[nq] = *reinterpret_cast<const s16x8*>(bufX + row * 128 + ((ch ^ (row & 7)) << 3));
    }
#pragma unroll
    for (int m = 0; m < 2; m++)
#pragma unroll
      for (int nq = 0; nq < 2; nq++)
        accA[m][nq] = __builtin_amdgcn_mfma_f32_16x16x32_bf16(af[m], bh[nq], accA[m][nq], 0, 0, 0);
  }
  __syncthreads();  // all phase-A reads of bufX/bufA done
  // in-place transform: bufX <- relu(a*x+d), ONE pass (c from chunk swizzle)
#pragma unroll
  for (int i = 0; i < 2; i++) {
    int q = tid + i * 512;
    int row = q >> 4, p = q & 15;
    int cb = (p ^ (row & 7)) * 8;
    u16x8 v = *reinterpret_cast<const u16x8*>(bufX + q * 8);
    u16x8 h;
#pragma unroll
    for (int j = 0; j < 8; j++)
      h[j] = f2bf(fmaxf(fmaf(aff_as[cb + j], bf2f(v[j]), aff_ds[cb + j]), 0.f));
    *reinterpret_cast<u16x8*>(bufX + q * 8) = h;
  }
  f32x4 acc[2][2] = {};
  for (int kh = 0; kh < K_; kh += 128) {
    if (tid < 128) bias_s[tid] = dubias[kh + tid];
#pragma unroll
    for (int i = 0; i < 4; i++) {
      int call = wid * 4 + i;
      int row = call * 4 + (lane >> 4);
      int gch = (lane & 15) ^ (row & 7);
      gload_lds16(duwh + (size_t)(kh + row) * C_ + gch * 8, bufA + call * 512);
    }
    __syncthreads();  // transform visible + W staged
    // embed MFMA: acc1[k 128][n 64] — raw fragments; k split over 4 wr
    f32x4 acc1[2][2] = {};
#pragma unroll
    for (int ks = 0; ks < 128; ks += 32) {
      const int ch = (ks >> 3) + l4;
      s16x8 af[2], bh[2];
#pragma unroll
      for (int m = 0; m < 2; m++) {
        int row = wr * 32 + m * 16 + l15;
        af[m] = *reinterpret_cast<const s16x8*>(bufA + row * 128 + ((ch ^ (row & 7)) << 3));
      }
#pragma unroll
      for (int nq = 0; nq < 2; nq++) {
        int row = wc * 32 + nq * 16 + l15;
        bh[nq] = *reinterpret_cast<const s16x8*>(bufX + row * 128 + ((ch ^ (row & 7)) << 3));
      }
#pragma unroll
      for (int m = 0; m < 2; m++)
#pragma unroll
        for (int nq = 0; nq < 2; nq++)
          acc1[m][nq] = __builtin_amdgcn_mfma_f32_16x16x32_bf16(af[m], bh[nq], acc1[m][nq], 0, 0, 0);
    }
    __syncthreads();  // all reads of bufA done before restage
    // issue M2 stage EARLY — its latency hides under the exp epilogue
#pragma unroll
    for (int i = 0; i < 4; i++) {
      int call = wid * 4 + i;
      int row = call * 4 + (lane >> 4);
      int gch = (lane & 15) ^ (row & 7);
      gload_lds16(M2h + (size_t)(b * C_ + row) * K_ + kh + gch * 8, bufA + call * 512);
    }
    // epilogue: P = exp(acc1+bias) -> bufP, packed u16x4 writes; register psums
    float pn[2] = {0.f, 0.f};
#pragma unroll
    for (int m = 0; m < 2; m++)
#pragma unroll
      for (int nq = 0; nq < 2; nq++) {
        int kl = wr * 32 + m * 16 + 4 * l4;
        int nl = wc * 32 + nq * 16 + l15;
        u16x4 pk;
#pragma unroll
        for (int r = 0; r < 4; r++) {
          unsigned short v = f2bf(__expf(acc1[m][nq][r] + bias_s[kl + r]));
          pk[r] = v;
          pn[nq] += bf2f(v);
        }
        int swzbase = (((kl >> 3) ^ (nl & 7)) << 3) | (kl & 7);
        *reinterpret_cast<u16x4*>(bufP + nl * 128 + swzbase) = pk;
      }
#pragma unroll
    for (int nq = 0; nq < 2; nq++) {
      pn[nq] += __shfl_xor(pn[nq], 16);
      pn[nq] += __shfl_xor(pn[nq], 32);
      if (l4 == 0) psum2[wr][wc * 32 + nq * 16 + l15] = pn[nq];
    }
    __syncthreads();  // bufP + bufA(M2) + psum2 ready
    if (tid < 64)
      psum_s[tid] += psum2[0][tid] + psum2[1][tid] + psum2[2][tid] + psum2[3][tid];
    // phase B MFMA: acc[o 128][n 64] += M2[o][k] @ P[n][k]; o split over 4 wr
#pragma unroll
    for (int ks = 0; ks < 128; ks += 32) {
      const int ch = (ks >> 3) + l4;
      s16x8 af[2], bh[2];
#pragma unroll
      for (int m = 0; m < 2; m++) {
        int row = wr * 32 + m * 16 + l15;
        af[m] = *reinterpret_cast<const s16x8*>(bufA + row * 128 + ((ch ^ (row & 7)) << 3));
      }
#pragma unroll
      for (int nq = 0; nq < 2; nq++) {
        int row = wc * 32 + nq * 16 + l15;
        bh[nq] = *reinterpret_cast<const s16x8*>(bufP + row * 128 + ((ch ^ (row & 7)) << 3));
      }
#pragma unroll
      for (int m = 0; m < 2; m++)
#pragma unroll
        for (int nq = 0; nq < 2; nq++)
          acc[m][nq] = __builtin_amdgcn_mfma_f32_16x16x32_bf16(af[m], bh[nq], acc[m][nq], 0, 0, 0);
    }
    __syncthreads();  // before next half overwrites bufA/bufP/bias_s/psum2
  }
  // out = accB * rs2 + accA + scb
#pragma unroll
  for (int m = 0; m < 2; m++)
#pragma unroll
    for (int nq = 0; nq < 2; nq++) {
      float rv = 1.f / psum_s[wc * 32 + nq * 16 + l15];
      int o = wr * 32 + m * 16 + 4 * l4;
      int nn = n0 + wc * 32 + nq * 16 + l15;
#pragma unroll
      for (int r = 0; r < 4; r++)
        out[(size_t)(b * C_ + o + r) * N_ + nn] =
            acc[m][nq][r] * rv + accA[m][nq][r] + scb_s[o + r];
    }
}

// ---------------------------------------------------------------------------
extern "C" void kernel_launch(void* const* d_in, const int* in_sizes, int n_in,
                              void* d_out, int out_size, void* d_ws, size_t ws_size,
                              hipStream_t stream) {
  (void)in_sizes; (void)n_in; (void)out_size; (void)ws_size;
  const float* x      = (const float*)d_in[0];
  const float* dpg    = (const float*)d_in[1];
  const float* dpb    = (const float*)d_in[2];
  const float* dpw    = (const float*)d_in[3];
  const float* dpbias = (const float*)d_in[4];
  const float* dug    = (const float*)d_in[5];
  const float* dub    = (const float*)d_in[6];
  const float* duw    = (const float*)d_in[7];
  const float* dubias = (const float*)d_in[8];
  const float* w1     = (const float*)d_in[9];
  const float* b1     = (const float*)d_in[10];
  const float* g1g    = (const float*)d_in[11];
  const float* g1b    = (const float*)d_in[12];
  const float* w2     = (const float*)d_in[13];
  const float* b2     = (const float*)d_in[14];
  const float* g2g    = (const float*)d_in[15];
  const float* g2b    = (const float*)d_in[16];
  const float* scw    = (const float*)d_in[17];
  const float* scb    = (const float*)d_in[18];
  float* out = (float*)d_out;
  float* ws  = (float*)d_ws;

  // workspace layout (float-slot units unless noted)
  float* part = ws;                                        // NSP*B*C*K = 8,388,608 fp32
  // post-xdown aliases inside the (then-dead) part region:
  unsigned short* g1h   = (unsigned short*)ws;             // 3,145,728 shorts
  unsigned short* g2h   = g1h + 3145728;                   // 3,145,728 shorts
  unsigned short* gmaxh = g2h + 3145728;                   // 524,288 shorts
  unsigned short* xh  = (unsigned short*)(ws + 16777216);  // B*N*C bf16
  float* base  = ws + 33554432;
  float* m_in  = base;               // 2048
  float* v_in  = m_in + 2048;
  float* r_in  = v_in + 2048;
  float* a_dp  = r_in + 2048;
  float* d_dp  = a_dp + 2048;
  float* a_du  = d_dp + 2048;
  float* d_du  = a_du + 2048;
  float* rden  = d_du + 2048;        // 4096
  float* xd    = rden + 4096;        // 524288 fp32 [b][p][k]
  float* Ut    = xd + 524288;        // 524288
  float* Vt    = Ut + 524288;        // 524288
  int*   idxb  = (int*)(Vt + 524288);  // 12288
  float* partS = (float*)(idxb + 12288);  // 12288
  float* partQ = partS + 12288;      // 12288
  float* pstS  = partQ + 12288;      // 262144 (128 chunks ×16b×128c)
  float* pstQ  = pstS + 262144;      // 262144
  float* pS    = pstQ + 262144;      // 65536 (NSP×16b×256k)
  unsigned short* xdh  = (unsigned short*)(pS + 65536);     // 524288 shorts
  unsigned short* dpwh = xdh + 524288;     // 32768
  unsigned short* duwh = dpwh + 32768;     // 32768
  unsigned short* scah = duwh + 32768;     // 16384
  unsigned short* scbh = scah + 16384;     // 16384
  unsigned short* w1sh = scbh + 16384;     // 65536
  unsigned short* w1bh = w1sh + 65536;     // 65536
  unsigned short* w2h  = w1bh + 65536;     // 65536
  unsigned short* M2h  = w2h + 65536;      // 524288 shorts

  k_prep<<<dim3(128, 16), 256, 0, stream>>>(x, xh, pstS, pstQ);
  k_wconv<<<dim3(256), 256, 0, stream>>>(dpw, duw, scw, w1, w2,
                                         dpwh, duwh, scah, scbh, w1sh, w1bh, w2h);
  k_instat_fin<<<dim3(8), 256, 0, stream>>>(pstS, pstQ, m_in, v_in, r_in);
  k_affine<<<1, 128, 0, stream>>>(m_in, v_in, r_in, dpg, dpb, dug, dub, a_dp, d_dp, a_du, d_du);
  k_dp_fused<<<dim3(NSP, 16), 512, 0, stream>>>(xh, dpwh, a_dp, d_dp, dpbias, part, pS);
  k_rowfin<<<dim3(16), 256, 0, stream>>>(pS, rden);
  k_xdown_red<<<dim3(2048), 256, 0, stream>>>(part, rden, xd, xdh);
  k_knn<<<dim3(16, 16), 256, 0, stream>>>(xd, idxb);
  k_uv_mfma<<<dim3(2, 2, 16), 256, 0, stream>>>(xdh, w1sh, w1bh, Ut, Vt);
  k_edge_t<<<dim3(768), 256, 0, stream>>>(Ut, Vt, idxb, b1, g1h);
  k_bnstat_t<<<dim3(48), 256, 0, stream>>>(g1h, partS, partQ);
  k_conv2_mfma<<<dim3(6, 2, 16), 256, 0, stream>>>(g1h, w2h, b2, partS, partQ, g1g, g1b, g2h);
  k_bnstat_t<<<dim3(48), 256, 0, stream>>>(g2h, partS, partQ);
  k_gmax_t<<<dim3(2, 16), 256, 0, stream>>>(g2h, partS, partQ, g2g, g2b, gmaxh);
  k_m2_mfma<<<dim3(2, 16), 256, 0, stream>>>(gmaxh, scbh, M2h);
  k_final_f<<<dim3(128, 16), 512, 0, stream>>>(xh, duwh, dubias, a_du, d_du, M2h, scah, scb, out);
}

// Round 24
// 207.256 us; speedup vs baseline: 1.0347x; 1.0347x over previous
//
#include <hip/hip_runtime.h>

typedef __attribute__((ext_vector_type(4))) float f32x4;
typedef __attribute__((ext_vector_type(8))) short s16x8;
typedef __attribute__((ext_vector_type(8))) unsigned short u16x8;
typedef __attribute__((ext_vector_type(4))) unsigned short u16x4;

namespace {
constexpr int B_ = 16, C_ = 128, N_ = 8192, K_ = 256, P_ = 128, NB_ = 6;
constexpr int NSP = 16;  // xdown n-splits
}

__device__ __forceinline__ float bf2f(unsigned short h) {
  return __uint_as_float(((unsigned int)h) << 16);
}
__device__ __forceinline__ unsigned short f2bf(float f) {
  unsigned int u = __float_as_uint(f);
  return (unsigned short)((u + 0x7fffu + ((u >> 16) & 1u)) >> 16);
}
// async global->LDS, 16B per lane, lane l writes lds_base + l*16
__device__ __forceinline__ void gload_lds16(const void* gsrc, void* ldsdst) {
  __builtin_amdgcn_global_load_lds(
      (const __attribute__((address_space(1))) void*)gsrc,
      (__attribute__((address_space(3))) void*)ldsdst, 16, 0, 0);
}

// ---------------------------------------------------------------------------
// 0) prep: xh[b][n][c] bf16 + xcn[b][c][n] bf16 + per-(chunk,b,c) IN partials
// ---------------------------------------------------------------------------
__global__ __launch_bounds__(256) void k_prep(const float* __restrict__ x,
                                              unsigned short* __restrict__ xh,
                                              unsigned short* __restrict__ xcn,
                                              float* __restrict__ pstS,
                                              float* __restrict__ pstQ) {
  const int chunk = blockIdx.x, b = blockIdx.y;
  const int n0 = chunk * 64;
  __shared__ float ts[64][132];
  __shared__ float rs_[2][128], rq_[2][128];
  const int tid = threadIdx.x;
  for (int i = 0; i < 8; i++) {
    int q = tid + i * 256;
    int n4 = q & 15, c = q >> 4;
    float4 v = *reinterpret_cast<const float4*>(x + (size_t)(b * C_ + c) * N_ + n0 + 4 * n4);
    ts[4 * n4 + 0][c] = v.x; ts[4 * n4 + 1][c] = v.y;
    ts[4 * n4 + 2][c] = v.z; ts[4 * n4 + 3][c] = v.w;
    u16x4 p; p[0] = f2bf(v.x); p[1] = f2bf(v.y); p[2] = f2bf(v.z); p[3] = f2bf(v.w);
    *reinterpret_cast<u16x4*>(xcn + (size_t)(b * C_ + c) * N_ + n0 + 4 * n4) = p;
  }
  __syncthreads();
  for (int i = 0; i < 4; i++) {
    int q = tid + i * 256;
    int cg = q & 15, nn = q >> 4;
    u16x8 o;
#pragma unroll
    for (int j = 0; j < 8; j++) o[j] = f2bf(ts[nn][8 * cg + j]);
    *reinterpret_cast<u16x8*>(xh + (size_t)(b * N_ + n0 + nn) * C_ + 8 * cg) = o;
  }
  {
    int c = tid & 127, h = tid >> 7;
    float s = 0.f, ss = 0.f;
    for (int nn = h * 32; nn < h * 32 + 32; nn++) { float v = ts[nn][c]; s += v; ss += v * v; }
    rs_[h][c] = s; rq_[h][c] = ss;
  }
  __syncthreads();
  if (tid < 128) {
    pstS[(chunk * 16 + b) * 128 + tid] = rs_[0][tid] + rs_[1][tid];
    pstQ[(chunk * 16 + b) * 128 + tid] = rq_[0][tid] + rq_[1][tid];
  }
}

// 0b) convert all weights to bf16 once
__global__ __launch_bounds__(256) void k_wconv(const float* __restrict__ dpw,
                                               const float* __restrict__ duw,
                                               const float* __restrict__ scw,
                                               const float* __restrict__ w1,
                                               const float* __restrict__ w2,
                                               unsigned short* __restrict__ dpwh,
                                               unsigned short* __restrict__ duwh,
                                               unsigned short* __restrict__ scah,
                                               unsigned short* __restrict__ scbh,
                                               unsigned short* __restrict__ w1sh,
                                               unsigned short* __restrict__ w1bh,
                                               unsigned short* __restrict__ w2h) {
  int t = blockIdx.x * 256 + threadIdx.x;
  if (t < 65536) {
    int o = t >> 8, k = t & 255;
    float vb = w1[(size_t)o * 512 + 256 + k];
    w1sh[t] = f2bf(w1[(size_t)o * 512 + k] + vb);
    w1bh[t] = f2bf(vb);
    w2h[t] = f2bf(w2[t]);
  }
  if (t < 32768) { dpwh[t] = f2bf(dpw[t]); duwh[t] = f2bf(duw[t]); }
  if (t < 16384) {
    int o = t >> 7, c = t & 127;
    scah[t] = f2bf(scw[o * 256 + c]);
    scbh[t] = f2bf(scw[o * 256 + 128 + c]);
  }
}

// 0c) finalize instance-norm stats per (b,c): 8 blocks x 256 threads
__global__ __launch_bounds__(256) void k_instat_fin(const float* __restrict__ pstS,
                                                    const float* __restrict__ pstQ,
                                                    float* __restrict__ m_o,
                                                    float* __restrict__ v_o,
                                                    float* __restrict__ r_o) {
  int e = blockIdx.x * 256 + threadIdx.x;  // b*128+c (2048)
  int b = e >> 7, c = e & 127;
  float s = 0.f, q = 0.f;
  for (int ch = 0; ch < 128; ch++) {
    s += pstS[(ch * 16 + b) * 128 + c];
    q += pstQ[(ch * 16 + b) * 128 + c];
  }
  float m = s / N_;
  float v = q / N_ - m * m;
  m_o[e] = m; v_o[e] = v; r_o[e] = rsqrtf(v + 1e-3f);
}

// 2) fold IN+BN into per-(b,c) affine (BN mean of IN(x) is analytically 0)
__global__ void k_affine(const float* __restrict__ m_in, const float* __restrict__ v_in,
                         const float* __restrict__ r_in,
                         const float* __restrict__ dpg, const float* __restrict__ dpb,
                         const float* __restrict__ dug, const float* __restrict__ dub,
                         float* __restrict__ a_dp, float* __restrict__ d_dp,
                         float* __restrict__ a_du, float* __restrict__ d_du) {
  int c = threadIdx.x;  // 128 threads
  float V = 0.f;
  for (int b = 0; b < B_; b++) { float v = v_in[b * C_ + c]; V += v / (v + 1e-3f); }
  V *= (1.f / B_);
  float R = rsqrtf(V + 1e-5f);
  float gdp = dpg[c], bdp = dpb[c], gdu = dug[c], bdu = dub[c];
  for (int b = 0; b < B_; b++) {
    int i = b * C_ + c;
    float r = r_in[i], m = m_in[i];
    float sdp = r * R * gdp;
    a_dp[i] = sdp; d_dp[i] = -m * sdp + bdp;
    float sdu = r * R * gdu;
    a_du[i] = sdu; d_du[i] = -m * sdu + bdu;
  }
}

// ---------------------------------------------------------------------------
// 3+5 fused (dp path), v7b: hconv folded in — stage RAW xh chunk, one
//   in-place LDS transform per chunk; C(next) issued BEFORE the transform so
//   its HBM latency hides under the transform VALU + next MFMA1.
//   3 barriers/chunk: MFMA1 -> P -> B1 -> issue X(next) -> MFMA2 -> B2 ->
//   issue C(next) -> transform bufH -> B3.
// ---------------------------------------------------------------------------
__global__ __launch_bounds__(512) void k_dp_fused(const unsigned short* __restrict__ xh,
                                                  const unsigned short* __restrict__ xcn,
                                                  const unsigned short* __restrict__ dpwh,
                                                  const float* __restrict__ a_dp,
                                                  const float* __restrict__ d_dp,
                                                  const float* __restrict__ dpbias,
                                                  float* __restrict__ part,
                                                  float* __restrict__ pS) {
  const int sp = blockIdx.x, b = blockIdx.y;
  const int nbase = sp * (N_ / NSP);  // 512-point split
  __shared__ __align__(16) unsigned short bufW[256 * 128];  // 64 KB [k][c]
  __shared__ __align__(16) unsigned short bufH[64 * 128];   // 16 KB x->h [n][c]
  __shared__ __align__(16) unsigned short bufP[256 * 64];   // 32 KB P [k][n]
  __shared__ __align__(16) unsigned short bufC[128 * 64];   // 16 KB x [c][n]
  __shared__ float bias_s[256], aff_as[128], aff_ds[128];
  const int tid = threadIdx.x, lane = tid & 63, wid = tid >> 6;  // 8 waves
  const int wr = wid >> 1, wc = wid & 1, l15 = lane & 15, l4 = lane >> 4;
  if (tid < 256) bias_s[tid] = dpbias[tid];
  if (tid < 128) { aff_as[tid] = a_dp[b * C_ + tid]; aff_ds[tid] = d_dp[b * C_ + tid]; }
  // stage full W [256 k][128 c]: 64 calls, 8 per wave
#pragma unroll
  for (int i = 0; i < 8; i++) {
    int call = wid * 8 + i;
    int row = call * 4 + (lane >> 4);
    int gch = (lane & 15) ^ (row & 7);
    gload_lds16(dpwh + (size_t)row * C_ + gch * 8, bufW + call * 512);
  }
  // prologue: stage X(0) raw, C(0)
#pragma unroll
  for (int i = 0; i < 2; i++) {
    int call = wid * 2 + i;
    int row = call * 4 + (lane >> 4);
    int gch = (lane & 15) ^ (row & 7);
    gload_lds16(xh + (size_t)(b * N_ + nbase + row) * C_ + gch * 8, bufH + call * 512);
  }
#pragma unroll
  for (int i = 0; i < 2; i++) {
    int call = wid * 2 + i;
    int row = call * 8 + (lane >> 3);
    int gch = (lane & 7) ^ (row & 7);
    gload_lds16(xcn + (size_t)(b * C_ + row) * N_ + nbase + gch * 8, bufC + call * 512);
  }
  __syncthreads();  // W + X(0) + C(0) staged
  // transform X(0) in place: bufH <- relu(a*x+d)
#pragma unroll
  for (int i = 0; i < 2; i++) {
    int q = tid + i * 512;
    int row = q >> 4, p = q & 15;
    int cb = (p ^ (row & 7)) * 8;
    u16x8 v = *reinterpret_cast<const u16x8*>(bufH + q * 8);
    u16x8 h;
#pragma unroll
    for (int j = 0; j < 8; j++)
      h[j] = f2bf(fmaxf(fmaf(aff_as[cb + j], bf2f(v[j]), aff_ds[cb + j]), 0.f));
    *reinterpret_cast<u16x8*>(bufH + q * 8) = h;
  }
  __syncthreads();  // transform visible
  s16x8 onesf;
#pragma unroll
  for (int j = 0; j < 8; j++) onesf[j] = (short)0x3F80;  // bf16 1.0
  f32x4 acc2[2][8] = {};
  f32x4 accS[8] = {};
  for (int nc = 0; nc < N_ / NSP; nc += 64) {
    const int n0n = nbase + nc + 64;  // next chunk base
    const bool more = (nc + 64) < (N_ / NSP);
    // MFMA1 embed: acc1[k 256][n 64] — raw fragments both sides
    f32x4 acc1[4][2] = {};
#pragma unroll
    for (int ks = 0; ks < 128; ks += 32) {
      const int ch = (ks >> 3) + l4;
      s16x8 af[4], bh[2];
#pragma unroll
      for (int m = 0; m < 4; m++) {
        int row = wr * 64 + m * 16 + l15;
        af[m] = *reinterpret_cast<const s16x8*>(bufW + row * 128 + ((ch ^ (row & 7)) << 3));
      }
#pragma unroll
      for (int nq = 0; nq < 2; nq++) {
        int row = wc * 32 + nq * 16 + l15;
        bh[nq] = *reinterpret_cast<const s16x8*>(bufH + row * 128 + ((ch ^ (row & 7)) << 3));
      }
#pragma unroll
      for (int m = 0; m < 4; m++)
#pragma unroll
        for (int nq = 0; nq < 2; nq++)
          acc1[m][nq] = __builtin_amdgcn_mfma_f32_16x16x32_bf16(af[m], bh[nq], acc1[m][nq], 0, 0, 0);
    }
    // P = exp(acc1 + bias) -> bufP (separate buffer)
#pragma unroll
    for (int m = 0; m < 4; m++)
#pragma unroll
      for (int nq = 0; nq < 2; nq++) {
        int kl = wr * 64 + m * 16 + 4 * l4;
        int nl = wc * 32 + nq * 16 + l15;
#pragma unroll
        for (int r = 0; r < 4; r++) {
          unsigned short v = f2bf(__expf(acc1[m][nq][r] + bias_s[kl + r]));
          bufP[(kl + r) * 64 + ((((nl >> 3) ^ ((kl + r) & 7)) << 3) | (nl & 7))] = v;
        }
      }
    __syncthreads();  // B1: P visible; MFMA1 done (bufH free); C(cur) drained
    // issue X(next) raw — lands under MFMA2, drained at B2
    if (more) {
#pragma unroll
      for (int i = 0; i < 2; i++) {
        int call = wid * 2 + i;
        int row = call * 4 + (lane >> 4);
        int gch = (lane & 15) ^ (row & 7);
        gload_lds16(xh + (size_t)(b * N_ + n0n + row) * C_ + gch * 8, bufH + call * 512);
      }
    }
    // MFMA2 xdown: acc2[c 128][k 256] += x @ P^T; ones-row -> accS (wr==0 only)
#pragma unroll
    for (int ks = 0; ks < 64; ks += 32) {
      const int ch = (ks >> 3) + l4;
      s16x8 af2[2], bp[8];
#pragma unroll
      for (int m = 0; m < 2; m++) {
        int row = wr * 32 + m * 16 + l15;
        af2[m] = *reinterpret_cast<const s16x8*>(bufC + row * 64 + ((ch ^ (row & 7)) << 3));
      }
#pragma unroll
      for (int nn = 0; nn < 8; nn++) {
        int row = wc * 128 + nn * 16 + l15;
        bp[nn] = *reinterpret_cast<const s16x8*>(bufP + row * 64 + ((ch ^ (row & 7)) << 3));
      }
#pragma unroll
      for (int m = 0; m < 2; m++)
#pragma unroll
        for (int nn = 0; nn < 8; nn++)
          acc2[m][nn] = __builtin_amdgcn_mfma_f32_16x16x32_bf16(af2[m], bp[nn], acc2[m][nn], 0, 0, 0);
      if (wr == 0) {
#pragma unroll
        for (int nn = 0; nn < 8; nn++)
          accS[nn] = __builtin_amdgcn_mfma_f32_16x16x32_bf16(onesf, bp[nn], accS[nn], 0, 0, 0);
      }
    }
    __syncthreads();  // B2: MFMA2 done (bufC/bufP free); X(next) drained
    if (more) {
      // issue C(next) FIRST — HBM latency hides under transform + next MFMA1
#pragma unroll
      for (int i = 0; i < 2; i++) {
        int call = wid * 2 + i;
        int row = call * 8 + (lane >> 3);
        int gch = (lane & 7) ^ (row & 7);
        gload_lds16(xcn + (size_t)(b * C_ + row) * N_ + n0n + gch * 8, bufC + call * 512);
      }
      // transform X(next) in place (visible at B3, read by next MFMA1)
#pragma unroll
      for (int i = 0; i < 2; i++) {
        int q = tid + i * 512;
        int row = q >> 4, p = q & 15;
        int cb = (p ^ (row & 7)) * 8;
        u16x8 v = *reinterpret_cast<const u16x8*>(bufH + q * 8);
        u16x8 h;
#pragma unroll
        for (int j = 0; j < 8; j++)
          h[j] = f2bf(fmaxf(fmaf(aff_as[cb + j], bf2f(v[j]), aff_ds[cb + j]), 0.f));
        *reinterpret_cast<u16x8*>(bufH + q * 8) = h;
      }
      __syncthreads();  // B3: transform visible
    }
  }
#pragma unroll
  for (int m = 0; m < 2; m++)
#pragma unroll
    for (int nn = 0; nn < 8; nn++) {
      int c = wr * 32 + m * 16 + 4 * l4;
      int k = wc * 128 + nn * 16 + l15;
#pragma unroll
      for (int r = 0; r < 4; r++)
        part[((size_t)(sp * B_ + b) * C_ + c + r) * K_ + k] = acc2[m][nn][r];
    }
  if (wr == 0 && l4 == 0) {
#pragma unroll
    for (int nn = 0; nn < 8; nn++)
      pS[((size_t)sp * 16 + b) * 256 + wc * 128 + nn * 16 + l15] = accS[nn][0];
  }
}

// 4a) rden[b][k] = 1 / sum over NSP split partials
__global__ __launch_bounds__(256) void k_rowfin(const float* __restrict__ pS,
                                                float* __restrict__ rden) {
  int e = blockIdx.x * 256 + threadIdx.x;  // b*256+k (4096)
  int b = e >> 8, k = e & 255;
  float s = 0.f;
  for (int sp = 0; sp < NSP; sp++) s += pS[((size_t)sp * 16 + b) * 256 + k];
  rden[e] = 1.f / s;
}

// 6) reduce split partials, scale by 1/den -> xd fp32 [b][p][k] + xdh bf16
__global__ __launch_bounds__(256) void k_xdown_red(const float* __restrict__ part,
                                                   const float* __restrict__ rden,
                                                   float* __restrict__ xd,
                                                   unsigned short* __restrict__ xdh) {
  int e = blockIdx.x * 256 + threadIdx.x;  // B*C*K
  int k = e % K_;
  int b = e / (K_ * C_);
  float s = 0.f;
  for (int sp = 0; sp < NSP; sp++) s += part[(size_t)sp * (B_ * C_ * K_) + e];
  float v = s * rden[b * K_ + k];
  xd[e] = v;
  xdh[e] = f2bf(v);
}

// ---------------------------------------------------------------------------
// 7) fused gram + sq + top-6: grid (16, 16), 8 p-rows per block.
// ---------------------------------------------------------------------------
__global__ __launch_bounds__(256) void k_knn(const float* __restrict__ xd,
                                             int* __restrict__ idx) {
  const int p0 = blockIdx.x * 8, b = blockIdx.y;
  __shared__ float A[8][256];
  __shared__ float Bt[32][132];
  __shared__ float pd_s[8][129];
  __shared__ float sq_s[128], sqh[128];
  const int tid = threadIdx.x;
#pragma unroll
  for (int i = 0; i < 2; i++) {
    int t = tid + i * 256;
    int pp = t >> 6, k4 = t & 63;
    float4 v = *reinterpret_cast<const float4*>(xd + (size_t)(b * C_ + p0 + pp) * K_ + 4 * k4);
    *reinterpret_cast<float4*>(&A[pp][4 * k4]) = v;
  }
  const int q = tid & 127, h = tid >> 7;
  float acc[4] = {};
  float sqacc = 0.f;
  for (int k0 = 0; k0 < K_; k0 += 32) {
    for (int i = 0; i < 4; i++) {
      int t = tid + i * 256;
      int qq = t >> 3, k4 = t & 7;
      float4 v = *reinterpret_cast<const float4*>(xd + (size_t)(b * C_ + qq) * K_ + k0 + 4 * k4);
      Bt[4 * k4 + 0][qq] = v.x; Bt[4 * k4 + 1][qq] = v.y;
      Bt[4 * k4 + 2][qq] = v.z; Bt[4 * k4 + 3][qq] = v.w;
    }
    __syncthreads();
    for (int kk = 0; kk < 32; ++kk) {
      float bv = Bt[kk][q];
#pragma unroll
      for (int i = 0; i < 4; ++i) acc[i] = fmaf(A[h * 4 + i][k0 + kk], bv, acc[i]);
    }
    {
      float s = 0.f;
      for (int kk = h * 16; kk < h * 16 + 16; kk++) { float v = Bt[kk][q]; s += v * v; }
      sqacc += s;
    }
    __syncthreads();
  }
  if (h == 1) sqh[q] = sqacc;
#pragma unroll
  for (int i = 0; i < 4; ++i) pd_s[h * 4 + i][q] = acc[i];
  __syncthreads();
  if (tid < 128) sq_s[tid] = sqacc + sqh[tid];
  __syncthreads();
  const int wv = tid >> 6, lane = tid & 63;
  for (int r = 0; r < 2; r++) {
    int p = wv * 2 + r;
    float v0 = 2.f * pd_s[p][lane] - sq_s[lane];
    float v1 = 2.f * pd_s[p][lane + 64] - sq_s[lane + 64];
    int q0 = lane, q1 = lane + 64;
#pragma unroll
    for (int j = 0; j < NB_; j++) {
      float bv; int bq;
      if (v0 > v1 || (v0 == v1 && q0 < q1)) { bv = v0; bq = q0; } else { bv = v1; bq = q1; }
#pragma unroll
      for (int o = 32; o > 0; o >>= 1) {
        float ov = __shfl_xor(bv, o); int oq = __shfl_xor(bq, o);
        if (ov > bv || (ov == bv && oq < bq)) { bv = ov; bq = oq; }
      }
      if (lane == 0) idx[(b * P_ + p0 + p) * NB_ + j] = bq;
      if (q0 == bq) v0 = -3.0e38f;
      if (q1 == bq) v1 = -3.0e38f;
    }
  }
}

// ---------------------------------------------------------------------------
// 8) UV via MFMA: Ut/Vt[b][p][o] = sum_k W1{sum|b}[o][k] * xdh[b][p][k]
// ---------------------------------------------------------------------------
__global__ __launch_bounds__(256) void k_uv_mfma(const unsigned short* __restrict__ xdh,
                                                 const unsigned short* __restrict__ w1sh,
                                                 const unsigned short* __restrict__ w1bh,
                                                 float* __restrict__ Ut, float* __restrict__ Vt) {
  const int o0 = blockIdx.x * 128, which = blockIdx.y, b = blockIdx.z;
  __shared__ __align__(16) unsigned char smemraw[128 * 132 * 4];
  unsigned short* tA = (unsigned short*)smemraw;
  unsigned short* tB = tA + 128 * 128;
  const unsigned short* wsel = which ? w1bh : w1sh;
  const int tid = threadIdx.x, lane = tid & 63, wid = tid >> 6;
  const int wr = wid >> 1, wc = wid & 1, l15 = lane & 15, l4 = lane >> 4;
  f32x4 acc[4][4] = {};
  for (int kh = 0; kh < 256; kh += 128) {
#pragma unroll
    for (int i = 0; i < 8; i++) {
      int call = wid * 8 + i;
      int row = call * 4 + (lane >> 4);
      int gch = (lane & 15) ^ (row & 7);
      gload_lds16(wsel + (size_t)(o0 + row) * 256 + kh + gch * 8, tA + call * 512);
      gload_lds16(xdh + (size_t)(b * P_ + row) * 256 + kh + gch * 8, tB + call * 512);
    }
    __syncthreads();
#pragma unroll
    for (int ks = 0; ks < 128; ks += 32) {
      const int ch = (ks >> 3) + l4;
      s16x8 af[4], bfv[4];
#pragma unroll
      for (int m = 0; m < 4; m++) {
        int row = wr * 64 + m * 16 + l15;
        af[m] = *reinterpret_cast<const s16x8*>(tA + row * 128 + ((ch ^ (row & 7)) << 3));
      }
#pragma unroll
      for (int n = 0; n < 4; n++) {
        int row = wc * 64 + n * 16 + l15;
        bfv[n] = *reinterpret_cast<const s16x8*>(tB + row * 128 + ((ch ^ (row & 7)) << 3));
      }
#pragma unroll
      for (int m = 0; m < 4; m++)
#pragma unroll
        for (int n = 0; n < 4; n++)
          acc[m][n] = __builtin_amdgcn_mfma_f32_16x16x32_bf16(af[m], bfv[n], acc[m][n], 0, 0, 0);
    }
    __syncthreads();
  }
  float (*ef)[132] = (float(*)[132])smemraw;
#pragma unroll
  for (int m = 0; m < 4; m++)
#pragma unroll
    for (int n = 0; n < 4; n++) {
      int ol = wr * 64 + m * 16 + 4 * l4;
      int pl = wc * 64 + n * 16 + l15;
#pragma unroll
      for (int r = 0; r < 4; r++) ef[pl][ol + r] = acc[m][n][r];
    }
  __syncthreads();
  float* outp = which ? Vt : Ut;
  for (int i = 0; i < 16; i++) {
    int q = tid + i * 256;
    int pl = q >> 5, c4 = q & 31;
    float4 v = *reinterpret_cast<const float4*>(&ef[pl][c4 * 4]);
    *reinterpret_cast<float4*>(outp + (size_t)(b * P_ + pl) * 256 + o0 + c4 * 4) = v;
  }
}

// 9) g1h[b*768+pj][o] = Ut[b][p][o] + b1[o] - Vt[b][q][o]   (bf16, coalesced)
__global__ __launch_bounds__(256) void k_edge_t(const float* __restrict__ Ut,
                                                const float* __restrict__ Vt,
                                                const int* __restrict__ idx,
                                                const float* __restrict__ b1,
                                                unsigned short* __restrict__ g1h) {
  __shared__ float b1s[256];
  const int tid = threadIdx.x;
  b1s[tid] = b1[tid];
  __syncthreads();
  const int row0 = blockIdx.x * 16;
  for (int r = 0; r < 16; r++) {
    int row = row0 + r;  // b*768 + p*6 + j
    int b = row / 768, pj = row % 768, p = pj / 6;
    int q = idx[(b * P_ + p) * NB_ + (pj % 6)];
    float v = Ut[(size_t)(b * P_ + p) * 256 + tid] + b1s[tid]
            - Vt[(size_t)(b * P_ + q) * 256 + tid];
    g1h[(size_t)row * 256 + tid] = f2bf(v);
  }
}

// 10) BN stats over rows of gt [12288][256]: per-block partial sums
__global__ __launch_bounds__(256) void k_bnstat_t(const unsigned short* __restrict__ gt,
                                                  float* __restrict__ partS,
                                                  float* __restrict__ partQ) {
  const int tid = threadIdx.x;
  const size_t row0 = (size_t)blockIdx.x * 256;
  float s = 0.f, ss = 0.f;
  for (int r = 0; r < 256; r++) {
    float v = bf2f(gt[(row0 + r) * 256 + tid]);
    s += v; ss += v * v;
  }
  partS[blockIdx.x * 256 + tid] = s;
  partQ[blockIdx.x * 256 + tid] = ss;
}

// 11) conv2 via MFMA (bn1 finalize folded in)
__global__ __launch_bounds__(256) void k_conv2_mfma(const unsigned short* __restrict__ g1h,
                                                    const unsigned short* __restrict__ w2h,
                                                    const float* __restrict__ b2,
                                                    const float* __restrict__ partS,
                                                    const float* __restrict__ partQ,
                                                    const float* __restrict__ gamma,
                                                    const float* __restrict__ beta,
                                                    unsigned short* __restrict__ g2h) {
  const int n0 = blockIdx.x * 128, o0 = blockIdx.y * 128, b = blockIdx.z;
  __shared__ __align__(16) unsigned short smem[2 * 128 * 128];
  unsigned short* tA = smem;
  unsigned short* tB = smem + 128 * 128;
  __shared__ float scs[256], shs[256], b2s[128];
  const int tid = threadIdx.x, lane = tid & 63, wid = tid >> 6;
  const int wr = wid >> 1, wc = wid & 1, l15 = lane & 15, l4 = lane >> 4;
  {
    float s = 0.f, q = 0.f;
    for (int i = 0; i < 48; i++) { s += partS[i * 256 + tid]; q += partQ[i * 256 + tid]; }
    const float cnt = (float)(B_ * P_ * NB_);
    float m = s / cnt, var = q / cnt - m * m;
    float scale = gamma[tid] * rsqrtf(var + 1e-5f);
    scs[tid] = scale; shs[tid] = -m * scale + beta[tid];
  }
  if (tid < 128) b2s[tid] = b2[o0 + tid];
  f32x4 acc[4][4] = {};
  for (int kh = 0; kh < 256; kh += 128) {
#pragma unroll
    for (int i = 0; i < 8; i++) {
      int call = wid * 8 + i;
      int row = call * 4 + (lane >> 4);
      int gch = (lane & 15) ^ (row & 7);
      gload_lds16(w2h + (size_t)(o0 + row) * 256 + kh + gch * 8, tA + call * 512);
      gload_lds16(g1h + (size_t)(b * 768 + n0 + row) * 256 + kh + gch * 8, tB + call * 512);
    }
    __syncthreads();
#pragma unroll
    for (int ks = 0; ks < 128; ks += 32) {
      const int ch = (ks >> 3) + l4;
      s16x8 af[4], bfv[4];
#pragma unroll
      for (int m = 0; m < 4; m++) {
        int row = wr * 64 + m * 16 + l15;
        af[m] = *reinterpret_cast<const s16x8*>(tA + row * 128 + ((ch ^ (row & 7)) << 3));
      }
#pragma unroll
      for (int n = 0; n < 4; n++) {
        int row = wc * 64 + n * 16 + l15;
        s16x8 raw = *reinterpret_cast<const s16x8*>(tB + row * 128 + ((ch ^ (row & 7)) << 3));
        s16x8 h;
#pragma unroll
        for (int j = 0; j < 8; j++) {
          int c = kh + ks + 8 * l4 + j;
          h[j] = (short)f2bf(fmaxf(fmaf(scs[c], bf2f((unsigned short)raw[j]), shs[c]), 0.f));
        }
        bfv[n] = h;
      }
#pragma unroll
      for (int m = 0; m < 4; m++)
#pragma unroll
        for (int n = 0; n < 4; n++)
          acc[m][n] = __builtin_amdgcn_mfma_f32_16x16x32_bf16(af[m], bfv[n], acc[m][n], 0, 0, 0);
    }
    __syncthreads();
  }
  unsigned short (*e_s)[136] = reinterpret_cast<unsigned short(*)[136]>(smem);
#pragma unroll
  for (int m = 0; m < 4; m++)
#pragma unroll
    for (int n = 0; n < 4; n++) {
      int ol = wr * 64 + m * 16 + 4 * l4;
      int nl = wc * 64 + n * 16 + l15;
#pragma unroll
      for (int r = 0; r < 4; r++)
        e_s[nl][ol + r] = f2bf(acc[m][n][r] + b2s[ol + r]);
    }
  __syncthreads();
  for (int i = 0; i < 8; i++) {
    int q = tid + i * 256;
    int og = q & 15, nl = q >> 4;
    u16x8 v = *reinterpret_cast<const u16x8*>(&e_s[nl][8 * og]);
    *reinterpret_cast<u16x8*>(g2h + (size_t)(b * 768 + n0 + nl) * 256 + o0 + 8 * og) = v;
  }
}

// 13) gmaxh[b][k][p] = max_j relu(bn2(g2h[b*768+p*6+j][k]))  (bn2 folded in)
__global__ __launch_bounds__(256) void k_gmax_t(const unsigned short* __restrict__ g2h,
                                                const float* __restrict__ partS,
                                                const float* __restrict__ partQ,
                                                const float* __restrict__ gamma,
                                                const float* __restrict__ beta,
                                                unsigned short* __restrict__ gmaxh) {
  const int o0 = blockIdx.x * 128, b = blockIdx.y;
  __shared__ float scS[128], shS[128];
  const int tid = threadIdx.x;
  if (tid < 128) {
    int o = o0 + tid;
    float s = 0.f, q = 0.f;
    for (int i = 0; i < 48; i++) { s += partS[i * 256 + o]; q += partQ[i * 256 + o]; }
    const float cnt = (float)(B_ * P_ * NB_);
    float m = s / cnt, var = q / cnt - m * m;
    float scale = gamma[o] * rsqrtf(var + 1e-5f);
    scS[tid] = scale; shS[tid] = -m * scale + beta[o];
  }
  __syncthreads();
  const int ol = tid & 127, ph = tid >> 7;
  const int o = o0 + ol;
  const float sc = scS[ol], sh = shS[ol];
  for (int p8 = ph * 64; p8 < ph * 64 + 64; p8 += 8) {
    u16x8 pack;
#pragma unroll
    for (int pi = 0; pi < 8; pi++) {
      int p = p8 + pi;
      float m = 0.f;
#pragma unroll
      for (int j = 0; j < NB_; j++) {
        float v = bf2f(g2h[(size_t)(b * 768 + p * 6 + j) * 256 + o]);
        m = fmaxf(m, fmaf(sc, v, sh));
      }
      pack[pi] = f2bf(m);
    }
    *reinterpret_cast<u16x8*>(gmaxh + (size_t)(b * 256 + o) * P_ + p8) = pack;
  }
}

// 14) M2h[b][o2][k] = sum_c scwB[o2][c] * gmaxh[b][k][c]  (MFMA)
__global__ __launch_bounds__(256) void k_m2_mfma(const unsigned short* __restrict__ gmaxh,
                                                 const unsigned short* __restrict__ scbh,
                                                 unsigned short* __restrict__ M2h) {
  const int k0 = blockIdx.x * 128, b = blockIdx.y;
  __shared__ __align__(16) unsigned short smem[2 * 128 * 128];
  unsigned short* tA = smem;
  unsigned short* tB = smem + 128 * 128;
  const int tid = threadIdx.x, lane = tid & 63, wid = tid >> 6;
  const int wr = wid >> 1, wc = wid & 1, l15 = lane & 15, l4 = lane >> 4;
#pragma unroll
  for (int i = 0; i < 8; i++) {
    int call = wid * 8 + i;
    int row = call * 4 + (lane >> 4);
    int gch = (lane & 15) ^ (row & 7);
    gload_lds16(scbh + (size_t)row * P_ + gch * 8, tA + call * 512);
    gload_lds16(gmaxh + (size_t)(b * 256 + k0 + row) * P_ + gch * 8, tB + call * 512);
  }
  __syncthreads();
  f32x4 acc[4][4] = {};
#pragma unroll
  for (int ks = 0; ks < 128; ks += 32) {
    const int ch = (ks >> 3) + l4;
    s16x8 af[4], bfv[4];
#pragma unroll
    for (int m = 0; m < 4; m++) {
      int row = wr * 64 + m * 16 + l15;
      af[m] = *reinterpret_cast<const s16x8*>(tA + row * 128 + ((ch ^ (row & 7)) << 3));
    }
#pragma unroll
    for (int n = 0; n < 4; n++) {
      int row = wc * 64 + n * 16 + l15;
      bfv[n] = *reinterpret_cast<const s16x8*>(tB + row * 128 + ((ch ^ (row & 7)) << 3));
    }
#pragma unroll
    for (int m = 0; m < 4; m++)
#pragma unroll
      for (int n = 0; n < 4; n++)
        acc[m][n] = __builtin_amdgcn_mfma_f32_16x16x32_bf16(af[m], bfv[n], acc[m][n], 0, 0, 0);
  }
  __syncthreads();
  unsigned short (*e_s)[136] = reinterpret_cast<unsigned short(*)[136]>(smem);
#pragma unroll
  for (int m = 0; m < 4; m++)
#pragma unroll
    for (int n = 0; n < 4; n++) {
      int ol = wr * 64 + m * 16 + 4 * l4;
      int kl = wc * 64 + n * 16 + l15;
#pragma unroll
      for (int r = 0; r < 4; r++)
        e_s[ol + r][kl] = f2bf(acc[m][n][r]);
    }
  __syncthreads();
  for (int i = 0; i < 8; i++) {
    int q = tid + i * 256;
    int kg = q & 15, oo = q >> 4;
    u16x8 v = *reinterpret_cast<const u16x8*>(&e_s[oo][8 * kg]);
    *reinterpret_cast<u16x8*>(M2h + (size_t)(b * C_ + oo) * K_ + k0 + 8 * kg) = v;
  }
}

// ---------------------------------------------------------------------------
// 15+16 fused (du path), v8: v7 + M2 stage issued BEFORE the exp epilogue
//   (HBM latency hides under the exp VALU). 512 threads, 8 waves.
// ---------------------------------------------------------------------------
__global__ __launch_bounds__(512) void k_final_f(const unsigned short* __restrict__ xh,
                                                 const unsigned short* __restrict__ duwh,
                                                 const float* __restrict__ dubias,
                                                 const float* __restrict__ a_du,
                                                 const float* __restrict__ d_du,
                                                 const unsigned short* __restrict__ M2h,
                                                 const unsigned short* __restrict__ scah,
                                                 const float* __restrict__ scb,
                                                 float* __restrict__ out) {
  const int n0 = blockIdx.x * 64, b = blockIdx.y;
  __shared__ __align__(16) unsigned short bufX[64 * 128];   // 16 KB xh->h [n][c]
  __shared__ __align__(16) unsigned short bufA[128 * 128];  // 32 KB scah / W half / M2 half
  __shared__ __align__(16) unsigned short bufP[64 * 128];   // 16 KB P half [n][k]
  __shared__ float aff_as[128], aff_ds[128], scb_s[128], bias_s[128];
  __shared__ float psum_s[64], psum2[4][64];
  const int tid = threadIdx.x, lane = tid & 63, wid = tid >> 6;  // 8 waves
  const int wr = wid >> 1, wc = wid & 1, l15 = lane & 15, l4 = lane >> 4;  // wr 0..3
  if (tid < 128) {
    aff_as[tid] = a_du[b * C_ + tid];
    aff_ds[tid] = d_du[b * C_ + tid];
    scb_s[tid] = scb[tid];
  }
  if (tid < 64) psum_s[tid] = 0.f;
  // stage raw xh tile (16 calls, 2/wave) + scah (32 calls, 4/wave)
#pragma unroll
  for (int i = 0; i < 2; i++) {
    int call = wid * 2 + i;
    int row = call * 4 + (lane >> 4);
    int gch = (lane & 15) ^ (row & 7);
    gload_lds16(xh + (size_t)(b * N_ + n0 + row) * C_ + gch * 8, bufX + call * 512);
  }
#pragma unroll
  for (int i = 0; i < 4; i++) {
    int call = wid * 4 + i;
    int row = call * 4 + (lane >> 4);
    int gch = (lane & 15) ^ (row & 7);
    gload_lds16(scah + (size_t)row * C_ + gch * 8, bufA + call * 512);
  }
  __syncthreads();
  // phase A: accA = scah[o][c] @ raw xh[n][c]; o split over 4 wr, n over 2 wc
  f32x4 accA[2][2] = {};
#pragma unroll
  for (int ks = 0; ks < 128; ks += 32) {
    const int ch = (ks >> 3) + l4;
    s16x8 af[2], bh[2];
#pragma unroll
    for (int m = 0; m < 2; m++) {
      int row = wr * 32 + m * 16 + l15;
      af[m] = *reinterpret_cast<const s16x8*>(bufA + row * 128 + ((ch ^ (row & 7)) << 3));
    }
#pragma unroll
    for (int nq = 0; nq < 2; nq++) {
      int row = wc * 32 + nq * 16 + l15;
      bh[nq] = *reinterpret_cast<const s16x8*>(bufX + row * 128 + ((ch ^ (row & 7)) << 3));
    }
#pragma unroll
    for (int m = 0; m < 2; m++)
#pragma unroll
      for (int nq = 0; nq < 2; nq++)
        accA[m][nq] = __builtin_amdgcn_mfma_f32_16x16x32_bf16(af[m], bh[nq], accA[m][nq], 0, 0, 0);
  }
  __syncthreads();  // all phase-A reads of bufX/bufA done
  // in-place transform: bufX <- relu(a*x+d), ONE pass (c from chunk swizzle)
#pragma unroll
  for (int i = 0; i < 2; i++) {
    int q = tid + i * 512;
    int row = q >> 4, p = q & 15;
    int cb = (p ^ (row & 7)) * 8;
    u16x8 v = *reinterpret_cast<const u16x8*>(bufX + q * 8);
    u16x8 h;
#pragma unroll
    for (int j = 0; j < 8; j++)
      h[j] = f2bf(fmaxf(fmaf(aff_as[cb + j], bf2f(v[j]), aff_ds[cb + j]), 0.f));
    *reinterpret_cast<u16x8*>(bufX + q * 8) = h;
  }
  f32x4 acc[2][2] = {};
  for (int kh = 0; kh < K_; kh += 128) {
    if (tid < 128) bias_s[tid] = dubias[kh + tid];
#pragma unroll
    for (int i = 0; i < 4; i++) {
      int call = wid * 4 + i;
      int row = call * 4 + (lane >> 4);
      int gch = (lane & 15) ^ (row & 7);
      gload_lds16(duwh + (size_t)(kh + row) * C_ + gch * 8, bufA + call * 512);
    }
    __syncthreads();  // transform visible + W staged
    // embed MFMA: acc1[k 128][n 64] — raw fragments; k split over 4 wr
    f32x4 acc1[2][2] = {};
#pragma unroll
    for (int ks = 0; ks < 128; ks += 32) {
      const int ch = (ks >> 3) + l4;
      s16x8 af[2], bh[2];
#pragma unroll
      for (int m = 0; m < 2; m++) {
        int row = wr * 32 + m * 16 + l15;
        af[m] = *reinterpret_cast<const s16x8*>(bufA + row * 128 + ((ch ^ (row & 7)) << 3));
      }
#pragma unroll
      for (int nq = 0; nq < 2; nq++) {
        int row = wc * 32 + nq * 16 + l15;
        bh[nq] = *reinterpret_cast<const s16x8*>(bufX + row * 128 + ((ch ^ (row & 7)) << 3));
      }
#pragma unroll
      for (int m = 0; m < 2; m++)
#pragma unroll
        for (int nq = 0; nq < 2; nq++)
          acc1[m][nq] = __builtin_amdgcn_mfma_f32_16x16x32_bf16(af[m], bh[nq], acc1[m][nq], 0, 0, 0);
    }
    __syncthreads();  // all reads of bufA done before restage
    // issue M2 stage EARLY — its latency hides under the exp epilogue
#pragma unroll
    for (int i = 0; i < 4; i++) {
      int call = wid * 4 + i;
      int row = call * 4 + (lane >> 4);
      int gch = (lane & 15) ^ (row & 7);
      gload_lds16(M2h + (size_t)(b * C_ + row) * K_ + kh + gch * 8, bufA + call * 512);
    }
    // epilogue: P = exp(acc1+bias) -> bufP, packed u16x4 writes; register psums
    float pn[2] = {0.f, 0.f};
#pragma unroll
    for (int m = 0; m < 2; m++)
#pragma unroll
      for (int nq = 0; nq < 2; nq++) {
        int kl = wr * 32 + m * 16 + 4 * l4;
        int nl = wc * 32 + nq * 16 + l15;
        u16x4 pk;
#pragma unroll
        for (int r = 0; r < 4; r++) {
          unsigned short v = f2bf(__expf(acc1[m][nq][r] + bias_s[kl + r]));
          pk[r] = v;
          pn[nq] += bf2f(v);
        }
        int swzbase = (((kl >> 3) ^ (nl & 7)) << 3) | (kl & 7);
        *reinterpret_cast<u16x4*>(bufP + nl * 128 + swzbase) = pk;
      }
#pragma unroll
    for (int nq = 0; nq < 2; nq++) {
      pn[nq] += __shfl_xor(pn[nq], 16);
      pn[nq] += __shfl_xor(pn[nq], 32);
      if (l4 == 0) psum2[wr][wc * 32 + nq * 16 + l15] = pn[nq];
    }
    __syncthreads();  // bufP + bufA(M2) + psum2 ready
    if (tid < 64)
      psum_s[tid] += psum2[0][tid] + psum2[1][tid] + psum2[2][tid] + psum2[3][tid];
    // phase B MFMA: acc[o 128][n 64] += M2[o][k] @ P[n][k]; o split over 4 wr
#pragma unroll
    for (int ks = 0; ks < 128; ks += 32) {
      const int ch = (ks >> 3) + l4;
      s16x8 af[2], bh[2];
#pragma unroll
      for (int m = 0; m < 2; m++) {
        int row = wr * 32 + m * 16 + l15;
        af[m] = *reinterpret_cast<const s16x8*>(bufA + row * 128 + ((ch ^ (row & 7)) << 3));
      }
#pragma unroll
      for (int nq = 0; nq < 2; nq++) {
        int row = wc * 32 + nq * 16 + l15;
        bh[nq] = *reinterpret_cast<const s16x8*>(bufP + row * 128 + ((ch ^ (row & 7)) << 3));
      }
#pragma unroll
      for (int m = 0; m < 2; m++)
#pragma unroll
        for (int nq = 0; nq < 2; nq++)
          acc[m][nq] = __builtin_amdgcn_mfma_f32_16x16x32_bf16(af[m], bh[nq], acc[m][nq], 0, 0, 0);
    }
    __syncthreads();  // before next half overwrites bufA/bufP/bias_s/psum2
  }
  // out = accB * rs2 + accA + scb
#pragma unroll
  for (int m = 0; m < 2; m++)
#pragma unroll
    for (int nq = 0; nq < 2; nq++) {
      float rv = 1.f / psum_s[wc * 32 + nq * 16 + l15];
      int o = wr * 32 + m * 16 + 4 * l4;
      int nn = n0 + wc * 32 + nq * 16 + l15;
#pragma unroll
      for (int r = 0; r < 4; r++)
        out[(size_t)(b * C_ + o + r) * N_ + nn] =
            acc[m][nq][r] * rv + accA[m][nq][r] + scb_s[o + r];
    }
}

// ---------------------------------------------------------------------------
extern "C" void kernel_launch(void* const* d_in, const int* in_sizes, int n_in,
                              void* d_out, int out_size, void* d_ws, size_t ws_size,
                              hipStream_t stream) {
  (void)in_sizes; (void)n_in; (void)out_size; (void)ws_size;
  const float* x      = (const float*)d_in[0];
  const float* dpg    = (const float*)d_in[1];
  const float* dpb    = (const float*)d_in[2];
  const float* dpw    = (const float*)d_in[3];
  const float* dpbias = (const float*)d_in[4];
  const float* dug    = (const float*)d_in[5];
  const float* dub    = (const float*)d_in[6];
  const float* duw    = (const float*)d_in[7];
  const float* dubias = (const float*)d_in[8];
  const float* w1     = (const float*)d_in[9];
  const float* b1     = (const float*)d_in[10];
  const float* g1g    = (const float*)d_in[11];
  const float* g1b    = (const float*)d_in[12];
  const float* w2     = (const float*)d_in[13];
  const float* b2     = (const float*)d_in[14];
  const float* g2g    = (const float*)d_in[15];
  const float* g2b    = (const float*)d_in[16];
  const float* scw    = (const float*)d_in[17];
  const float* scb    = (const float*)d_in[18];
  float* out = (float*)d_out;
  float* ws  = (float*)d_ws;

  // workspace layout (float-slot units unless noted)
  float* part = ws;                                        // NSP*B*C*K = 8,388,608 fp32
  // post-xdown aliases inside the (then-dead) part region:
  unsigned short* g1h   = (unsigned short*)ws;             // 3,145,728 shorts
  unsigned short* g2h   = g1h + 3145728;                   // 3,145,728 shorts
  unsigned short* gmaxh = g2h + 3145728;                   // 524,288 shorts
  unsigned short* xh  = (unsigned short*)(ws + 16777216);  // B*N*C bf16
  unsigned short* xcn = (unsigned short*)(ws + 25165824);  // B*C*N bf16
  float* base  = ws + 33554432;
  float* m_in  = base;               // 2048
  float* v_in  = m_in + 2048;
  float* r_in  = v_in + 2048;
  float* a_dp  = r_in + 2048;
  float* d_dp  = a_dp + 2048;
  float* a_du  = d_dp + 2048;
  float* d_du  = a_du + 2048;
  float* rden  = d_du + 2048;        // 4096
  float* xd    = rden + 4096;        // 524288 fp32 [b][p][k]
  float* Ut    = xd + 524288;        // 524288
  float* Vt    = Ut + 524288;        // 524288
  int*   idxb  = (int*)(Vt + 524288);  // 12288
  float* partS = (float*)(idxb + 12288);  // 12288
  float* partQ = partS + 12288;      // 12288
  float* pstS  = partQ + 12288;      // 262144 (128 chunks ×16b×128c)
  float* pstQ  = pstS + 262144;      // 262144
  float* pS    = pstQ + 262144;      // 65536 (NSP×16b×256k)
  unsigned short* xdh  = (unsigned short*)(pS + 65536);     // 524288 shorts
  unsigned short* dpwh = xdh + 524288;     // 32768
  unsigned short* duwh = dpwh + 32768;     // 32768
  unsigned short* scah = duwh + 32768;     // 16384
  unsigned short* scbh = scah + 16384;     // 16384
  unsigned short* w1sh = scbh + 16384;     // 65536
  unsigned short* w1bh = w1sh + 65536;     // 65536
  unsigned short* w2h  = w1bh + 65536;     // 65536
  unsigned short* M2h  = w2h + 65536;      // 524288 shorts

  k_prep<<<dim3(128, 16), 256, 0, stream>>>(x, xh, xcn, pstS, pstQ);
  k_wconv<<<dim3(256), 256, 0, stream>>>(dpw, duw, scw, w1, w2,
                                         dpwh, duwh, scah, scbh, w1sh, w1bh, w2h);
  k_instat_fin<<<dim3(8), 256, 0, stream>>>(pstS, pstQ, m_in, v_in, r_in);
  k_affine<<<1, 128, 0, stream>>>(m_in, v_in, r_in, dpg, dpb, dug, dub, a_dp, d_dp, a_du, d_du);
  k_dp_fused<<<dim3(NSP, 16), 512, 0, stream>>>(xh, xcn, dpwh, a_dp, d_dp, dpbias, part, pS);
  k_rowfin<<<dim3(16), 256, 0, stream>>>(pS, rden);
  k_xdown_red<<<dim3(2048), 256, 0, stream>>>(part, rden, xd, xdh);
  k_knn<<<dim3(16, 16), 256, 0, stream>>>(xd, idxb);
  k_uv_mfma<<<dim3(2, 2, 16), 256, 0, stream>>>(xdh, w1sh, w1bh, Ut, Vt);
  k_edge_t<<<dim3(768), 256, 0, stream>>>(Ut, Vt, idxb, b1, g1h);
  k_bnstat_t<<<dim3(48), 256, 0, stream>>>(g1h, partS, partQ);
  k_conv2_mfma<<<dim3(6, 2, 16), 256, 0, stream>>>(g1h, w2h, b2, partS, partQ, g1g, g1b, g2h);
  k_bnstat_t<<<dim3(48), 256, 0, stream>>>(g2h, partS, partQ);
  k_gmax_t<<<dim3(2, 16), 256, 0, stream>>>(g2h, partS, partQ, g2g, g2b, gmaxh);
  k_m2_mfma<<<dim3(2, 16), 256, 0, stream>>>(gmaxh, scbh, M2h);
  k_final_f<<<dim3(128, 16), 512, 0, stream>>>(xh, duwh, dubias, a_du, d_du, M2h, scah, scb, out);
}